// Round 3
// baseline (352.511 us; speedup 1.0000x reference)
//
#include <hip/hip_runtime.h>
#include <hip/hip_bf16.h>
#include <stdint.h>

// Problem constants (fixed by reference: B=8, Q=4096, E=1024, M=256)
#define TOK 32768
#define EMB 1024
#define MSL 256

typedef __attribute__((ext_vector_type(8))) short short8;   // 8 bf16 = 4 VGPRs (MFMA A/B frag)
typedef __attribute__((ext_vector_type(4))) float f32x4;    // MFMA C/D frag

// raw barrier: lgkm drain only — outstanding global_load_lds / global loads
// (next-tile prefetch) deliberately stay in flight across the barrier.
#define SBAR() asm volatile("s_waitcnt lgkmcnt(0)\n\ts_barrier" ::: "memory")

__device__ __forceinline__ ushort f2bf(float f) {
    union { float f; uint32_t u; } c; c.f = f;
    uint32_t u = c.u;
    return (ushort)((u + 0x7fffu + ((u >> 16) & 1u)) >> 16);  // RNE
}

// truncation split: f = hi + lo with |f - hi - lo| <= 2^-16 |f|
__device__ __forceinline__ void split2(float f, ushort& h, ushort& l) {
    union { float f; uint32_t u; } c; c.f = f;
    h = (ushort)(c.u >> 16);
    union { uint32_t u; float f; } hv; hv.u = c.u & 0xffff0000u;
    union { float f; uint32_t u; } lc; lc.f = f - hv.f;
    l = (ushort)(lc.u >> 16);
}

__device__ __forceinline__ void async_copy16(const void* gsrc, void* ldst) {
    // wave-uniform LDS base + lane*16 semantics (guide §5)
    __builtin_amdgcn_global_load_lds(
        (const __attribute__((address_space(1))) uint32_t*)gsrc,
        (__attribute__((address_space(3))) uint32_t*)ldst,
        16, 0, 0);
}

// XOR swizzle: LDS slot (row, c) holds global 16B-chunk (c ^ (row&7)) of that row.
// Writers keep lane-flat LDS addresses (global source permuted -> same coalescing);
// readers XOR the chunk column by row&7 -> 16-lane phases spread over all 32 banks.

// =====================================================================
// pre_small: merged tiny precomputes (all independent of each other)
// =====================================================================
__global__ __launch_bounds__(256) void pre_small(
    const float* __restrict__ Wq, ushort* __restrict__ wqth, ushort* __restrict__ wqtl,
    const float* __restrict__ mb, ushort* __restrict__ mbh, ushort* __restrict__ mbl,
    const float* __restrict__ bq, float* __restrict__ cvec)
{
    __shared__ float ld[64 * 65];
    const int b = blockIdx.x;
    const int t = threadIdx.x;
    if (b < 256) {
        const int eBase = (b & 15) * 64;
        const int fBase = (b >> 4) * 64;
        #pragma unroll
        for (int r = 0; r < 16; ++r) {
            int row = r * 4 + (t >> 6);      // f within tile
            int col = t & 63;                // e within tile
            ld[row * 65 + col] = Wq[(size_t)(fBase + row) * EMB + eBase + col];
        }
        __syncthreads();
        #pragma unroll
        for (int r = 0; r < 16; ++r) {
            int row = r * 4 + (t >> 6);      // e within tile
            int col = t & 63;                // f within tile
            float v = ld[col * 65 + row];    // = Wq[fBase+col][eBase+row]
            ushort h, l; split2(v, h, l);
            size_t o = (size_t)(eBase + row) * EMB + fBase + col;
            wqth[o] = h; wqtl[o] = l;
        }
    } else if (b < 512) {
        int i = (b - 256) * 256 + t;         // mb: 256*1024/4 float4s
        float4 v = ((const float4*)mb)[i];
        ushort4 h4, l4;
        split2(v.x, h4.x, l4.x); split2(v.y, h4.y, l4.y);
        split2(v.z, h4.z, l4.z); split2(v.w, h4.w, l4.w);
        ((ushort4*)mbh)[i] = h4;
        ((ushort4*)mbl)[i] = l4;
    } else {
        int m = (b - 512) * 4 + (t >> 6);
        int lane = t & 63;
        const float4* mrow = (const float4*)(mb + (size_t)m * EMB);
        const float4* brow = (const float4*)bq;
        float s = 0.f;
        #pragma unroll
        for (int k = 0; k < 4; ++k) {
            float4 a = mrow[lane + k * 64];
            float4 bb = brow[lane + k * 64];
            s += a.x * bb.x + a.y * bb.y + a.z * bb.z + a.w * bb.w;
        }
        #pragma unroll
        for (int off = 32; off; off >>= 1) s += __shfl_xor(s, off, 64);
        if (lane == 0) cvec[m] = s;
    }
}

// =====================================================================
// Split-precision GEMM body (prologue GEMMs): see round-2 comments.
// =====================================================================
template<int MODE>
__device__ __forceinline__ void gemm_body(
    ushort* smem, const float* __restrict__ A,
    const ushort* __restrict__ Bh, const ushort* __restrict__ Bl,
    ushort* __restrict__ O1, ushort* __restrict__ O2,
    int K, int ldc, int bx, int by)
{
    ushort* sAh = smem;            // [128][64] = 8192 ushorts each
    ushort* sAl = smem + 8192;
    ushort* sBh = smem + 16384;
    ushort* sBl = smem + 24576;

    const int t = threadIdx.x;
    const int lane = t & 63;
    const int wave = t >> 6;
    const int wr = wave >> 1;
    const int wc = wave & 1;
    const int rowBase = by * 128;
    const int colBase = bx * 128;

    const float*  Ab  = A  + (size_t)rowBase * K;
    const ushort* Bhb = Bh + (size_t)colBase * K;
    const ushort* Blb = Bl + (size_t)colBase * K;

    const int cg = ((t & 7) ^ ((t >> 3) & 7)) << 3;

    f32x4 acc[4][4] = {};

    const int kIters = K >> 6;
    for (int kt = 0; kt < kIters; ++kt) {
        const int k0 = kt << 6;
        __syncthreads();
        #pragma unroll
        for (int r = 0; r < 4; ++r) {
            int row = r * 32 + (t >> 3);
            async_copy16(Bhb + (size_t)row * K + k0 + cg, &sBh[(size_t)(r * 256 + wave * 64) * 8]);
            async_copy16(Blb + (size_t)row * K + k0 + cg, &sBl[(size_t)(r * 256 + wave * 64) * 8]);
        }
        #pragma unroll
        for (int r = 0; r < 4; ++r) {
            int i = r * 256 + t;
            int row = r * 32 + (t >> 3);
            const float* src = Ab + (size_t)row * K + k0 + cg;
            float4 f0 = *(const float4*)src;
            float4 f1 = *(const float4*)(src + 4);
            short8 hv, lv; ushort h, l;
            split2(f0.x, h, l); hv[0] = (short)h; lv[0] = (short)l;
            split2(f0.y, h, l); hv[1] = (short)h; lv[1] = (short)l;
            split2(f0.z, h, l); hv[2] = (short)h; lv[2] = (short)l;
            split2(f0.w, h, l); hv[3] = (short)h; lv[3] = (short)l;
            split2(f1.x, h, l); hv[4] = (short)h; lv[4] = (short)l;
            split2(f1.y, h, l); hv[5] = (short)h; lv[5] = (short)l;
            split2(f1.z, h, l); hv[6] = (short)h; lv[6] = (short)l;
            split2(f1.w, h, l); hv[7] = (short)h; lv[7] = (short)l;
            *(short8*)&sAh[(size_t)i * 8] = hv;
            *(short8*)&sAl[(size_t)i * 8] = lv;
        }
        __syncthreads();

        #pragma unroll
        for (int ks = 0; ks < 2; ++ks) {
            const int kc = ks * 4 + (lane >> 4);
            short8 ah[4], al[4], bh[4], bl[4];
            #pragma unroll
            for (int i2 = 0; i2 < 4; ++i2) {
                int row = wr * 64 + i2 * 16 + (lane & 15);
                int off = row * 64 + ((kc ^ (row & 7)) << 3);
                ah[i2] = *(const short8*)&sAh[off];
                al[i2] = *(const short8*)&sAl[off];
            }
            #pragma unroll
            for (int j = 0; j < 4; ++j) {
                int row = wc * 64 + j * 16 + (lane & 15);
                int off = row * 64 + ((kc ^ (row & 7)) << 3);
                bh[j] = *(const short8*)&sBh[off];
                bl[j] = *(const short8*)&sBl[off];
            }
            #pragma unroll
            for (int i2 = 0; i2 < 4; ++i2)
                #pragma unroll
                for (int j = 0; j < 4; ++j) {
                    acc[i2][j] = __builtin_amdgcn_mfma_f32_16x16x32_bf16(ah[i2], bh[j], acc[i2][j], 0, 0, 0);
                    acc[i2][j] = __builtin_amdgcn_mfma_f32_16x16x32_bf16(ah[i2], bl[j], acc[i2][j], 0, 0, 0);
                    acc[i2][j] = __builtin_amdgcn_mfma_f32_16x16x32_bf16(al[i2], bh[j], acc[i2][j], 0, 0, 0);
                }
        }
    }

    // epilogue: C/D layout col=lane&15, row=(lane>>4)*4+reg  [verified m89/m91]
    #pragma unroll
    for (int i2 = 0; i2 < 4; ++i2) {
        #pragma unroll
        for (int j = 0; j < 4; ++j) {
            const int col = colBase + wc * 64 + j * 16 + (lane & 15);
            #pragma unroll
            for (int r = 0; r < 4; ++r) {
                const int row = rowBase + wr * 64 + i2 * 16 + ((lane >> 4) << 2) + r;
                float v = acc[i2][j][r];
                if (MODE == 0) {
                    ushort h, l; split2(v, h, l);
                    O1[(size_t)row * ldc + col] = h;
                    O2[(size_t)row * ldc + col] = l;
                } else {
                    int fc = row >> 6, jj = (row & 63) >> 4, lanelo = row & 15;
                    int cc = col >> 3, ksx = cc >> 2, lanehi = cc & 3, e = col & 7;
                    size_t idx = ((((size_t)fc * 8 + ksx) * 4 + jj) * 64 + lanehi * 16 + lanelo) * 8 + e;
                    O1[idx] = f2bf(v);
                }
            }
        }
    }
}

// pre_gemms: blocks 0..15 -> P split (Ph/Pl); blocks 16..31 -> RT frag layout
__global__ __launch_bounds__(256) void pre_gemms(
    const float* __restrict__ mb, const ushort* __restrict__ wqth, const ushort* __restrict__ wqtl,
    const float* __restrict__ Wo, const ushort* __restrict__ mbh, const ushort* __restrict__ mbl,
    ushort* __restrict__ Ph, ushort* __restrict__ Pl, ushort* __restrict__ RTfrag)
{
    __shared__ ushort smem[32768];   // 64 KiB
    const int b = blockIdx.x;
    if (b < 16) {
        // P[m,e] = sum_f mb[m,f] * WqT[e,f] ; grid (8 cols x 2 rows)
        gemm_body<0>(smem, mb, wqth, wqtl, Ph, Pl, EMB, EMB, b & 7, b >> 3);
    } else {
        // RT[f,m] = sum_e Wo[f,e] * mb[m,e] ; grid (2 cols x 8 rows)
        const int id = b - 16;
        gemm_body<1>(smem, Wo, mbh, mbl, RTfrag, nullptr, EMB, 0, id & 1, id >> 1);
    }
}

// =====================================================================
// Fused: scores + softmax + PV + bias + residual. 128 tokens/block,
// 512 threads = 8 waves (2x4 in phase 1), 1 block/CU, 160 KiB LDS.
//
// Pipelined phase 1 (raw barriers, T3/T4-lite):
//   - B tiles (Ph/Pl strips) double-buffered; B(kt+1) copies issued inside
//     iter kt, AFTER the only register-read of in-flight loads (x-regs) --
//     so the compiler's vmcnt wait retires exactly B(kt) (issued a full
//     compute phase earlier -> near-zero stall) and never the prefetch.
//   - x rows prefetched to registers one iter ahead; split->ds_write->LDS.
//   - barriers are raw s_barrier + lgkmcnt(0) only: NO vmcnt(0) drain.
// Hazards: top barrier protects sA/buf[cur^1] overwrite vs previous compute
// reads; mid barrier publishes sA ds_writes + guarantees (via the x-reg
// wait above) that every wave's B(kt) copies have landed.
//
// LDS map (ushort idx): sAh 0..8191 [128][64], sAl 8192..16383,
//   buf0 Bh 16384..32767 / Bl 32768..49151, buf1 Bh 49152..65535 /
//   Bl 65536..81919. Softmax redM/redS overlay sAh[0..2047];
//   sW[128][256] overlays buf0 (last compute reads buf1: kt=15 odd).
// Phase 2: barrier-free; weight A-frags in regs, RT B-frags coalesced
// from the precomputed fragment-layout buffer (L2-resident 512 KB).
// =====================================================================
__global__ __launch_bounds__(512, 2) void fused_attn(
    const float* __restrict__ x, const ushort* __restrict__ Ph,
    const ushort* __restrict__ Pl, const float* __restrict__ cvec,
    const ushort* __restrict__ RTfrag, const float* __restrict__ bo,
    float* __restrict__ out)
{
    __shared__ ushort smem[81920];            // 160 KiB exactly
    ushort* sAh = smem;                       // [128][64]
    ushort* sAl = smem + 8192;
    ushort* sW  = smem + 16384;               // [128][256] swizzled (phase 2)
    float*  redM = (float*)&smem[0];          // [4][128] partial max (post-ph1)
    float*  redS = (float*)&smem[1024];       // [4][128] partial sum

    const int t = threadIdx.x;
    const int lane = t & 63;
    const int wave = t >> 6;                  // 0..7
    const int wr = wave >> 2;                 // 0..1 : token rows wr*64
    const int wc = wave & 3;                  // 0..3 : m cols wc*64
    const int rowBase = blockIdx.x * 128;

    const float* Ab = x + (size_t)rowBase * EMB;
    const int cg = ((t & 7) ^ ((t >> 3) & 7)) << 3;

    f32x4 acc[4][4] = {};
    float4 xr[2][2];

    // stage B(kt) strip (256 x 64 of Ph and Pl) into buffer base bb
    auto stageB = [&](int kt, ushort* bb) {
        const int k0 = kt << 6;
        ushort* bh = bb;
        ushort* bl = bb + 16384;
        #pragma unroll
        for (int r = 0; r < 4; ++r) {
            int row = r * 64 + (t >> 3);
            async_copy16(Ph + (size_t)row * EMB + k0 + cg, &bh[(size_t)(r * 512 + wave * 64) * 8]);
            async_copy16(Pl + (size_t)row * EMB + k0 + cg, &bl[(size_t)(r * 512 + wave * 64) * 8]);
        }
    };
    // prefetch x slice for kt into registers
    auto loadX = [&](int kt) {
        const int k0 = kt << 6;
        #pragma unroll
        for (int r = 0; r < 2; ++r) {
            const float* src = Ab + (size_t)(r * 64 + (t >> 3)) * EMB + k0 + cg;
            xr[r][0] = *(const float4*)src;
            xr[r][1] = *(const float4*)(src + 4);
        }
    };

    // prologue: B(0) then x(0) (program order matters: x loads are youngest,
    // so waiting on x-regs retires B too)
    stageB(0, smem + 16384);
    loadX(0);

    for (int kt = 0; kt < 16; ++kt) {
        SBAR();   // top: prev compute's LDS reads complete -> safe to overwrite
        // split x-regs -> sA (the x-reg read inserts the vmcnt wait that
        // also retires this kt's B copies)
        #pragma unroll
        for (int r = 0; r < 2; ++r) {
            int i = r * 512 + t;
            short8 hv, lv; ushort h, l;
            split2(xr[r][0].x, h, l); hv[0] = (short)h; lv[0] = (short)l;
            split2(xr[r][0].y, h, l); hv[1] = (short)h; lv[1] = (short)l;
            split2(xr[r][0].z, h, l); hv[2] = (short)h; lv[2] = (short)l;
            split2(xr[r][0].w, h, l); hv[3] = (short)h; lv[3] = (short)l;
            split2(xr[r][1].x, h, l); hv[4] = (short)h; lv[4] = (short)l;
            split2(xr[r][1].y, h, l); hv[5] = (short)h; lv[5] = (short)l;
            split2(xr[r][1].z, h, l); hv[6] = (short)h; lv[6] = (short)l;
            split2(xr[r][1].w, h, l); hv[7] = (short)h; lv[7] = (short)l;
            *(short8*)&sAh[(size_t)i * 8] = hv;
            *(short8*)&sAl[(size_t)i * 8] = lv;
        }
        // prefetch next tile (stays in flight across the barriers below)
        if (kt < 15) {
            stageB(kt + 1, ((kt + 1) & 1) ? (smem + 49152) : (smem + 16384));
            loadX(kt + 1);
        }
        SBAR();   // mid: sA published; all waves' B(kt) landed (drained above)

        const ushort* cbh = (kt & 1) ? (smem + 49152) : (smem + 16384);
        const ushort* cbl = cbh + 16384;
        #pragma unroll
        for (int ks = 0; ks < 2; ++ks) {
            const int kc = ks * 4 + (lane >> 4);
            short8 ah[4], al[4], bh[4], bl[4];
            #pragma unroll
            for (int i2 = 0; i2 < 4; ++i2) {
                int row = wr * 64 + i2 * 16 + (lane & 15);
                int off = row * 64 + ((kc ^ (row & 7)) << 3);
                ah[i2] = *(const short8*)&sAh[off];
                al[i2] = *(const short8*)&sAl[off];
            }
            #pragma unroll
            for (int j = 0; j < 4; ++j) {
                int row = wc * 64 + j * 16 + (lane & 15);
                int off = row * 64 + ((kc ^ (row & 7)) << 3);
                bh[j] = *(const short8*)&cbh[off];
                bl[j] = *(const short8*)&cbl[off];
            }
            #pragma unroll
            for (int i2 = 0; i2 < 4; ++i2)
                #pragma unroll
                for (int j = 0; j < 4; ++j) {
                    acc[i2][j] = __builtin_amdgcn_mfma_f32_16x16x32_bf16(ah[i2], bh[j], acc[i2][j], 0, 0, 0);
                    acc[i2][j] = __builtin_amdgcn_mfma_f32_16x16x32_bf16(ah[i2], bl[j], acc[i2][j], 0, 0, 0);
                    acc[i2][j] = __builtin_amdgcn_mfma_f32_16x16x32_bf16(al[i2], bh[j], acc[i2][j], 0, 0, 0);
                }
        }
    }

    // ---------------- softmax (128 rows; cols split over 4 wc groups) -------
    // (no async ops outstanding now -> plain __syncthreads is cheap & safe)
    {
        float cj[4];
        #pragma unroll
        for (int j = 0; j < 4; ++j) cj[j] = cvec[wc * 64 + j * 16 + (lane & 15)];
        #pragma unroll
        for (int i2 = 0; i2 < 4; ++i2)
            #pragma unroll
            for (int j = 0; j < 4; ++j)
                #pragma unroll
                for (int r = 0; r < 4; ++r) acc[i2][j][r] += cj[j];
    }
    float pmax[4][4];
    #pragma unroll
    for (int i2 = 0; i2 < 4; ++i2)
        #pragma unroll
        for (int r = 0; r < 4; ++r) {
            float m0 = fmaxf(fmaxf(acc[i2][0][r], acc[i2][1][r]),
                             fmaxf(acc[i2][2][r], acc[i2][3][r]));
            #pragma unroll
            for (int off = 8; off; off >>= 1) m0 = fmaxf(m0, __shfl_xor(m0, off, 64));
            pmax[i2][r] = m0;
        }
    __syncthreads();   // bar A: all phase-1 LDS reads complete (redM area safe)
    if ((lane & 15) == 0) {
        #pragma unroll
        for (int i2 = 0; i2 < 4; ++i2)
            #pragma unroll
            for (int r = 0; r < 4; ++r)
                redM[wc * 128 + wr * 64 + i2 * 16 + ((lane >> 4) << 2) + r] = pmax[i2][r];
    }
    __syncthreads();   // bar B
    {
        float psum[4][4];
        #pragma unroll
        for (int i2 = 0; i2 < 4; ++i2)
            #pragma unroll
            for (int r = 0; r < 4; ++r) {
                int R = wr * 64 + i2 * 16 + ((lane >> 4) << 2) + r;
                float mx = fmaxf(fmaxf(redM[R], redM[128 + R]),
                                 fmaxf(redM[256 + R], redM[384 + R]));
                float s = 0.f;
                #pragma unroll
                for (int j = 0; j < 4; ++j) {
                    float e = __expf(acc[i2][j][r] - mx);
                    acc[i2][j][r] = e;
                    s += e;
                }
                #pragma unroll
                for (int off = 8; off; off >>= 1) s += __shfl_xor(s, off, 64);
                psum[i2][r] = s;
            }
        if ((lane & 15) == 0) {
            #pragma unroll
            for (int i2 = 0; i2 < 4; ++i2)
                #pragma unroll
                for (int r = 0; r < 4; ++r)
                    redS[wc * 128 + wr * 64 + i2 * 16 + ((lane >> 4) << 2) + r] = psum[i2][r];
        }
    }
    __syncthreads();   // bar C
    // normalize -> bf16 weights -> swizzled sW[128][256]
    #pragma unroll
    for (int i2 = 0; i2 < 4; ++i2)
        #pragma unroll
        for (int r = 0; r < 4; ++r) {
            int R = wr * 64 + i2 * 16 + ((lane >> 4) << 2) + r;
            float tot = redS[R] + redS[128 + R] + redS[256 + R] + redS[384 + R];
            float inv = 1.0f / tot;
            #pragma unroll
            for (int j = 0; j < 4; ++j) {
                int col = wc * 64 + j * 16 + (lane & 15);
                int cc = col >> 3;
                int slot = (cc & 24) | ((cc & 7) ^ (R & 7));
                sW[R * 256 + slot * 8 + (lane & 7)] = f2bf(acc[i2][j][r] * inv);
            }
        }
    __syncthreads();   // bar D: sW complete

    // ---------------- phase 2: out = w @ RT^T + bo + x (barrier-free) -------
    const int wr2 = wave >> 1;    // 0..3 : token rows wr2*32
    const int wc2 = wave & 1;     // 0..1 : f cols wc2*32 within a 64-f chunk

    short8 af[2][8];
    #pragma unroll
    for (int i2 = 0; i2 < 2; ++i2) {
        int R = wr2 * 32 + i2 * 16 + (lane & 15);
        #pragma unroll
        for (int ks = 0; ks < 8; ++ks) {
            int cc = ks * 4 + (lane >> 4);
            int slot = (cc & 24) | ((cc & 7) ^ (R & 7));
            af[i2][ks] = *(const short8*)&sW[R * 256 + slot * 8];
        }
    }

    for (int fc = 0; fc < 16; ++fc) {
        f32x4 acc2[2][2] = {};
        #pragma unroll
        for (int ks = 0; ks < 8; ++ks) {
            short8 b[2];
            #pragma unroll
            for (int j = 0; j < 2; ++j) {
                int jj = wc2 * 2 + j;
                b[j] = *(const short8*)&RTfrag[((((size_t)fc * 8 + ks) * 4 + jj) * 64 + lane) * 8];
            }
            #pragma unroll
            for (int i2 = 0; i2 < 2; ++i2)
                #pragma unroll
                for (int j = 0; j < 2; ++j)
                    acc2[i2][j] = __builtin_amdgcn_mfma_f32_16x16x32_bf16(
                        af[i2][ks], b[j], acc2[i2][j], 0, 0, 0);
        }
        // epilogue: + bias + residual, fp32 store (x rows L2/L3-hot from ph1)
        #pragma unroll
        for (int i2 = 0; i2 < 2; ++i2)
            #pragma unroll
            for (int j = 0; j < 2; ++j) {
                int col = fc * 64 + wc2 * 32 + j * 16 + (lane & 15);
                float bcol = bo[col];
                #pragma unroll
                for (int r = 0; r < 4; ++r) {
                    int row = rowBase + wr2 * 32 + i2 * 16 + ((lane >> 4) << 2) + r;
                    out[(size_t)row * EMB + col] =
                        acc2[i2][j][r] + bcol + x[(size_t)row * EMB + col];
                }
            }
    }
}

extern "C" void kernel_launch(void* const* d_in, const int* in_sizes, int n_in,
                              void* d_out, int out_size, void* d_ws, size_t ws_size,
                              hipStream_t stream) {
    const float* x  = (const float*)d_in[0];   // [TOK, EMB]
    const float* mb = (const float*)d_in[1];   // [MSL, EMB]
    const float* Wq = (const float*)d_in[2];   // [EMB, EMB]
    const float* bq = (const float*)d_in[3];   // [EMB]
    const float* Wo = (const float*)d_in[4];   // [EMB, EMB]
    const float* bo = (const float*)d_in[5];   // [EMB]
    float* out = (float*)d_out;                // [TOK, EMB]

    // workspace layout (~6.5 MB), no atomic destinations -> no zeroing
    char* ws = (char*)d_ws;
    size_t o = 0;
    ushort* mbh    = (ushort*)(ws + o); o += (size_t)MSL * EMB * 2;   // mb hi
    ushort* mbl    = (ushort*)(ws + o); o += (size_t)MSL * EMB * 2;   // mb lo
    ushort* wqth   = (ushort*)(ws + o); o += (size_t)EMB * EMB * 2;   // Wq^T hi
    ushort* wqtl   = (ushort*)(ws + o); o += (size_t)EMB * EMB * 2;   // Wq^T lo
    ushort* Ph     = (ushort*)(ws + o); o += (size_t)MSL * EMB * 2;   // P hi [M][E]
    ushort* Pl     = (ushort*)(ws + o); o += (size_t)MSL * EMB * 2;   // P lo
    ushort* RTfrag = (ushort*)(ws + o); o += (size_t)EMB * MSL * 2;   // RT, frag layout
    float*  cvec   = (float*)(ws + o);  o += (size_t)MSL * 4;

    // 1) merged tiny precomputes (transpose+split Wq, split mb, cvec)
    pre_small<<<576, 256, 0, stream>>>(Wq, wqth, wqtl, mb, mbh, mbl, bq, cvec);

    // 2) both folded-projection GEMMs, direct-format epilogues
    pre_gemms<<<32, 256, 0, stream>>>(mb, wqth, wqtl, Wo, mbh, mbl, Ph, Pl, RTfrag);

    // 3) fused scores + softmax + PV + bias + residual (128 tokens/block,
    //    pipelined raw-barrier phase 1, 160 KiB LDS, 1 block/CU)
    fused_attn<<<TOK / 128, 512, 0, stream>>>(x, Ph, Pl, cvec, RTfrag, bo, out);
}